// Round 16
// baseline (356.905 us; speedup 1.0000x reference)
//
#include <hip/hip_runtime.h>
#include <hip/hip_bf16.h>

#define DIM 512
#define HID 2048
#define MT  64
#define KS1 8     // 512/64  k-steps GEMM1 (i8 K=64)
#define KS2 32    // 2048/64 k-steps GEMM2

typedef __attribute__((ext_vector_type(4))) int      i32x4;
typedef __attribute__((ext_vector_type(4))) unsigned u32x4;
typedef __attribute__((ext_vector_type(2))) unsigned u32x2;
typedef __attribute__((ext_vector_type(2))) __fp16   fp16x2;

// Explicit AGPR parking (unified file on gfx950; frees arch-VGPR budget).
#define ASET(ag, v) asm volatile("v_accvgpr_write_b32 %0, %1" : "=a"(ag) : "v"(v))
#define AGET(v, ag) asm volatile("v_accvgpr_read_b32 %0, %1" : "=v"(v) : "a"(ag))

// branch-free exact-erf GELU via Abramowitz-Stegun 7.1.26 (abs err 1.5e-7)
static __device__ __forceinline__ float gelu_erf(float h) {
  const float u  = h * 0.70710678118654752f;
  const float au = fabsf(u);
  const float t  = __builtin_amdgcn_rcpf(fmaf(0.3275911f, au, 1.f));
  float p = fmaf(1.061405429f, t, -1.453152027f);
  p = fmaf(p, t, 1.421413741f);
  p = fmaf(p, t, -0.284496736f);
  p = fmaf(p, t, 0.254829592f);
  p *= t;
  const float e  = __builtin_amdgcn_exp2f(-u * u * 1.4426950408889634f);  // exp(-u^2)
  const float ea = fmaf(-p, e, 1.f);                                      // erf(|u|)
  const float er = __builtin_copysignf(ea, u);
  return fmaf(0.5f * h, er, 0.5f * h);
}

static __device__ __forceinline__ int qi8(float g, float s) {
  return (int)fminf(fmaxf(rintf(g * s), -128.f), 127.f);
}

static __device__ __forceinline__ unsigned q4pack(float4 v, float scl) {
  int q0 = qi8(v.x, scl), q1 = qi8(v.y, scl), q2 = qi8(v.z, scl), q3 = qi8(v.w, scl);
  return (unsigned)(q0 & 255) | ((unsigned)(q1 & 255) << 8) |
         ((unsigned)(q2 & 255) << 16) | ((unsigned)(q3 & 255) << 24);
}

static __device__ __forceinline__ unsigned packf16(float a, float b) {
  fp16x2 v = __builtin_amdgcn_cvt_pkrtz(a, b);   // RTZ: |stored| <= |input|
  unsigned u; __builtin_memcpy(&u, &v, 4); return u;
}
static __device__ __forceinline__ float unpackf16(unsigned u, int hi) {
  unsigned short s = (unsigned short)(hi ? (u >> 16) : (u & 0xffff));
  __fp16 h; __builtin_memcpy(&h, &s, 2);
  return (float)h;
}
// 2x f16 -> 2x i8 quant packed into bits [0,16) of return (q0 | q1<<8)
static __device__ __forceinline__ unsigned q2f16(unsigned pv, float s) {
  const int q0 = qi8(gelu_erf(unpackf16(pv, 0)), s);
  const int q1 = qi8(gelu_erf(unpackf16(pv, 1)), s);
  return (unsigned)(q0 & 255) | ((unsigned)(q1 & 255) << 8);
}

// ---------------- K0: per-block partial sums of |w| ----------------
__global__ void k_wabs(const float* __restrict__ w1, const float* __restrict__ w2,
                       float* __restrict__ part) {
  const int b = blockIdx.x;
  const float* src = (b < 256 ? w1 : w2) + (size_t)(b & 255) * 4096 + threadIdx.x * 16;
  float s = 0.f;
#pragma unroll
  for (int i = 0; i < 4; ++i) {
    float4 v = *(const float4*)(src + i * 4);
    s += fabsf(v.x) + fabsf(v.y) + fabsf(v.z) + fabsf(v.w);
  }
  __shared__ float red[256];
  red[threadIdx.x] = s;
  __syncthreads();
  for (int off = 128; off > 0; off >>= 1) {
    if (threadIdx.x < (unsigned)off) red[threadIdx.x] += red[threadIdx.x + off];
    __syncthreads();
  }
  if (threadIdx.x == 0) part[b] = red[0];
}

// ---------------- K1: reduce partials (redundant per block, deterministic),
// ternary-quantize weights, pack i8 MFMA fragments.
__global__ void k_pack(const float* __restrict__ w1, const float* __restrict__ w2,
                       const float* __restrict__ part, float* __restrict__ scales,
                       signed char* __restrict__ p1, signed char* __restrict__ p2) {
  __shared__ float s1[256], s2[256];
  s1[threadIdx.x] = part[threadIdx.x];
  s2[threadIdx.x] = part[256 + threadIdx.x];
  __syncthreads();
  for (int off = 128; off > 0; off >>= 1) {
    if (threadIdx.x < (unsigned)off) {
      s1[threadIdx.x] += s1[threadIdx.x + off];
      s2[threadIdx.x] += s2[threadIdx.x + off];
    }
    __syncthreads();
  }
  const float mc1 = fmaxf(s1[0] / 1048576.f, 1e-5f);
  const float mc2 = fmaxf(s2[0] / 1048576.f, 1e-5f);
  if (blockIdx.x == 0 && threadIdx.x == 0) {
    scales[0] = mc1;
    scales[2] = mc2;
  }

  int slot = blockIdx.x * 256 + threadIdx.x;    // 0..131071 (first 65536 -> p1)
  const bool isw2 = slot >= 65536;
  const float* w = isw2 ? w2 : w1;
  const float scl = 1.f / (isw2 ? mc2 : mc1);
  signed char* p = isw2 ? p2 : p1;
  const int K  = isw2 ? HID : DIM;
  const int KS = isw2 ? KS2 : KS1;
  slot &= 65535;
  const int lane = slot & 63;
  const int fr   = slot >> 6;
  const int nt   = fr / KS;
  const int ks   = fr - nt * KS;
  const int n  = nt * 16 + (lane & 15);
  const int k0 = ks * 64 + (lane >> 4) * 16;
  const float* src = w + (size_t)n * K + k0;
  i32x4 outv;
#pragma unroll
  for (int d = 0; d < 4; ++d) {
    unsigned v = 0;
#pragma unroll
    for (int e = 0; e < 4; ++e) {
      int q = (int)fminf(fmaxf(rintf(src[d * 4 + e] * scl), -1.f), 1.f);
      v |= ((unsigned)(q & 255)) << (8 * e);
    }
    outv[d] = (int)v;
  }
  *(i32x4*)(p + (size_t)slot * 16) = outv;
}

// ---------------- K2: single-pass GEMM1; h cols 0..1023 as f16 in qh,
// cols 1024..2047 in AGPRs; in-place f16->i8 row halving; GEMM2; residual.
__global__ __launch_bounds__(1024, 4) void k_fused(
    const float* __restrict__ x, const float* __restrict__ b1,
    const float* __restrict__ b2, const signed char* __restrict__ p1,
    const signed char* __restrict__ p2, const float* __restrict__ scales,
    float* __restrict__ out) {
  __shared__ __align__(16) signed char qh[131072];  // f16 h [64][1024] -> i8 qh [64][2048]
  __shared__ __align__(16) signed char xq[32768];   // xq i8 [64][512] -> scratch

  float* rxTab = (float*)qh;                 // [64] — fully read before any qh write
  float* scrP  = (float*)xq;                 // [2*1024] partials (xq dead post-GEMM1)
  float* scrS  = (float*)(xq + 8192);        // [64] 127/maxg

  const int tid = threadIdx.x;
  const int wv = tid >> 6, ln = tid & 63, lg = ln >> 4, lr = ln & 15;
  const int tok0 = blockIdx.x * MT;
  const float wsc1 = scales[0], wsc2 = scales[2];
  const int swz = (lr & 7) << 4;             // row swizzle (row = mt*16+lr)

  // ---- phase 1: load x, per-token absmax int8 quant -> xq (swizzled)
  {
    const int row = tid >> 4, sub = tid & 15;
    const float4* xr = (const float4*)(x + (size_t)(tok0 + row) * DIM);
    float4 v[8];
    float am = 0.f;
#pragma unroll
    for (int i = 0; i < 8; ++i) {
      v[i] = xr[i * 16 + sub];
      am = fmaxf(am, fmaxf(fmaxf(fabsf(v[i].x), fabsf(v[i].y)),
                           fmaxf(fabsf(v[i].z), fabsf(v[i].w))));
    }
#pragma unroll
    for (int m = 1; m < 16; m <<= 1) am = fmaxf(am, __shfl_xor(am, m));
    const float mc  = fmaxf(am, 1e-5f);
    const float scl = 127.f / mc;
    if (sub == 0) rxTab[row] = mc * (1.f / 127.f) * wsc1;
    const int rswz = (row & 7) << 4;
#pragma unroll
    for (int i = 0; i < 8; ++i) {
      const unsigned u = q4pack(v[i], scl);
      const int k = i * 64 + sub * 4;
      *(unsigned*)&xq[row * DIM + (((k & ~15) ^ rswz) | (k & 15))] = u;
    }
  }
  __syncthreads();

  float rxw[4];
#pragma unroll
  for (int mt = 0; mt < 4; ++mt) rxw[mt] = rxTab[mt * 16 + lr];
  __syncthreads();   // rxTab reads complete before chunk epilogues write qh

  // ---- GEMM1 (swapped, single pass): ntg = ch*16 + wv.
  // chunks 0..3 (cols 0..1023): hv f16 -> qh; chunks 4..7: hv f16 -> AGPRs.
  unsigned hvB[4][4][2];      // [ch-4][mt][pr] — AGPR-parked, static indices only
  float hvmax[4], hvmin[4];
#pragma unroll
  for (int mt = 0; mt < 4; ++mt) { hvmax[mt] = -3.4e38f; hvmin[mt] = 3.4e38f; }

#define G1CHUNK(CH)                                                               \
  {                                                                               \
    i32x4 acc[4];                                                                 \
    _Pragma("unroll")                                                             \
    for (int mt = 0; mt < 4; ++mt) acc[mt] = (i32x4){0, 0, 0, 0};                 \
    const int ntg = (CH) * 16 + wv;                                               \
    _Pragma("unroll 2")                                                           \
    for (int ks = 0; ks < KS1; ++ks) {                                            \
      const i32x4 bfr =                                                           \
          *(const i32x4*)(p1 + ((size_t)(ntg * KS1 + ks) * 64 + ln) * 16);        \
      _Pragma("unroll")                                                           \
      for (int mt = 0; mt < 4; ++mt) {                                            \
        const i32x4 a = *(const i32x4*)&xq[(mt * 16 + lr) * DIM +                 \
                                           ((ks * 64 + lg * 16) ^ swz)];          \
        acc[mt] = __builtin_amdgcn_mfma_i32_16x16x64_i8(bfr, a, acc[mt],          \
                                                        0, 0, 0);                 \
      }                                                                           \
    }                                                                             \
    const float4 b4 = *(const float4*)&b1[ntg * 16 + lg * 4];                     \
    _Pragma("unroll")                                                             \
    for (int mt = 0; mt < 4; ++mt) {                                              \
      float hv[4];                                                                \
      _Pragma("unroll")                                                           \
      for (int r = 0; r < 4; ++r) {                                               \
        const float bias = r == 0 ? b4.x : r == 1 ? b4.y : r == 2 ? b4.z : b4.w;  \
        hv[r] = fmaf((float)acc[mt][r], rxw[mt], bias);                           \
        hvmax[mt] = fmaxf(hvmax[mt], hv[r]);                                      \
        hvmin[mt] = fminf(hvmin[mt], hv[r]);                                      \
      }                                                                           \
      const unsigned p0 = packf16(hv[0], hv[1]);                                  \
      const unsigned p1v = packf16(hv[2], hv[3]);                                 \
      if ((CH) < 4) {                                                             \
        const int row = mt * 16 + lr;                                             \
        const int bc  = ntg * 32 + lg * 8;  /* f16 byte col, %16 in {0,8} */      \
        u32x2 w2v; w2v[0] = p0; w2v[1] = p1v;                                     \
        *(u32x2*)&qh[row * 2048 + (((bc & ~15) ^ ((row & 7) << 4)) | (bc & 15))]  \
            = w2v;                                                                \
      } else {                                                                    \
        ASET(hvB[(CH) - 4][mt][0], p0);                                           \
        ASET(hvB[(CH) - 4][mt][1], p1v);                                          \
      }                                                                           \
    }                                                                             \
  }

  G1CHUNK(0)
  G1CHUNK(1)
  G1CHUNK(2)
  G1CHUNK(3)
  G1CHUNK(4)
  G1CHUNK(5)
  G1CHUNK(6)
  G1CHUNK(7)
#undef G1CHUNK
  __syncthreads();   // xq A-reads + qh f16 writes done

  // ---- per-row h range reduce; derive 127/max|gelu| per row
#pragma unroll
  for (int mt = 0; mt < 4; ++mt) {
    hvmax[mt] = fmaxf(hvmax[mt], __shfl_xor(hvmax[mt], 16));
    hvmax[mt] = fmaxf(hvmax[mt], __shfl_xor(hvmax[mt], 32));
    hvmin[mt] = fminf(hvmin[mt], __shfl_xor(hvmin[mt], 16));
    hvmin[mt] = fminf(hvmin[mt], __shfl_xor(hvmin[mt], 32));
  }
  if (ln < 16) {
#pragma unroll
    for (int mt = 0; mt < 4; ++mt) {
      scrP[wv * 64 + mt * 16 + lr] = hvmax[mt];
      scrP[1024 + wv * 64 + mt * 16 + lr] = hvmin[mt];
    }
  }
  __syncthreads();
  if (tid < MT) {
    float hx = scrP[tid], hn = scrP[1024 + tid];
#pragma unroll
    for (int w = 1; w < 16; ++w) {
      hx = fmaxf(hx, scrP[w * 64 + tid]);
      hn = fminf(hn, scrP[1024 + w * 64 + tid]);
    }
    // gelu monotone increasing on [-0.7518, inf); |gelu| <= 0.1699705 below.
    const float posg = gelu_erf(hx);
    const float negg = (hn <= -0.7518f) ? 0.1699705f : fabsf(gelu_erf(hn));
    scrS[tid] = 127.f / fmaxf(fmaxf(posg, negg), 1e-5f);
  }
  __syncthreads();

  float s2w[4];
#pragma unroll
  for (int mt = 0; mt < 4; ++mt) s2w[mt] = scrS[mt * 16 + lr];  // own rows

  // ---- conversion phase A: wave wv owns rows wv+16i; read full f16 row
  // (regs), convert, write i8 cols 0..1023 in place (bytes 0..1023).
  // Intra-wave read-before-write; no cross-wave overlap -> no inner barriers.
#pragma unroll
  for (int i = 0; i < 4; ++i) {
    const int rq  = wv + 16 * i;
    const int rsw = (rq & 7) << 4;
    const float sA = scrS[rq];                       // LDS broadcast
    // f16 cols [8ln,8ln+8) and [512+8ln,512+8ln+8)
    const u32x4 blkA = *(const u32x4*)&qh[rq * 2048 + ((16 * ln) ^ rsw)];
    const u32x4 blkB = *(const u32x4*)&qh[rq * 2048 + 1024 + ((16 * ln) ^ rsw)];
    unsigned oa0 = q2f16(blkA[0], sA) | (q2f16(blkA[1], sA) << 16);
    unsigned oa1 = q2f16(blkA[2], sA) | (q2f16(blkA[3], sA) << 16);
    unsigned ob0 = q2f16(blkB[0], sA) | (q2f16(blkB[1], sA) << 16);
    unsigned ob1 = q2f16(blkB[2], sA) | (q2f16(blkB[3], sA) << 16);
    const int c0 = 8 * ln;          // i8 col of first block
    const int c1 = 512 + 8 * ln;    // i8 col of second block
    u32x2 wa; wa[0] = oa0; wa[1] = oa1;
    u32x2 wb; wb[0] = ob0; wb[1] = ob1;
    *(u32x2*)&qh[rq * 2048 + (((c0 & ~15) ^ rsw) | (c0 & 15))] = wa;
    *(u32x2*)&qh[rq * 2048 + (((c1 & ~15) ^ rsw) | (c1 & 15))] = wb;
  }
  __syncthreads();   // all f16 consumed; low-half i8 in place

  // ---- conversion phase B: reg half (AGPRs) -> i8 cols 1024..2047 (static)
#pragma unroll
  for (int ch = 0; ch < 4; ++ch) {
#pragma unroll
    for (int mt = 0; mt < 4; ++mt) {
      const int ntg = (ch + 4) * 16 + wv;
      const int m = mt * 16 + lr;
      unsigned v0, v1;
      AGET(v0, hvB[ch][mt][0]);
      AGET(v1, hvB[ch][mt][1]);
      const unsigned pk = q2f16(v0, s2w[mt]) | (q2f16(v1, s2w[mt]) << 16);
      *(unsigned*)&qh[m * 2048 + (((ntg * 16) ^ ((m & 7) << 4)) + lg * 4)] = pk;
    }
  }
  __syncthreads();

  // ---- GEMM2 (swapped): [64 x 512] i8; natural rows; wave owns 2 n-tiles
  i32x4 acc2[2][4];
#pragma unroll
  for (int t = 0; t < 2; ++t)
#pragma unroll
    for (int mt = 0; mt < 4; ++mt) acc2[t][mt] = (i32x4){0, 0, 0, 0};
#pragma unroll 2
  for (int ks = 0; ks < KS2; ++ks) {
    i32x4 a[4];
#pragma unroll
    for (int mt = 0; mt < 4; ++mt)
      a[mt] = *(const i32x4*)&qh[(mt * 16 + lr) * 2048 + ((ks * 64 + lg * 16) ^ swz)];
#pragma unroll
    for (int t = 0; t < 2; ++t) {
      const int nt = wv * 2 + t;
      const i32x4 bfr = *(const i32x4*)(p2 + ((size_t)(nt * KS2 + ks) * 64 + ln) * 16);
#pragma unroll
      for (int mt = 0; mt < 4; ++mt)
        acc2[t][mt] = __builtin_amdgcn_mfma_i32_16x16x64_i8(bfr, a[mt], acc2[t][mt], 0, 0, 0);
    }
  }
#pragma unroll
  for (int t = 0; t < 2; ++t) {
    const int n0 = (wv * 2 + t) * 16 + lg * 4;
    const float4 b4 = *(const float4*)&b2[n0];
#pragma unroll
    for (int mt = 0; mt < 4; ++mt) {
      const int m = mt * 16 + lr;
      const float r2 = wsc2 * __builtin_amdgcn_rcpf(s2w[mt]);  // = maxg/127*wsc2
      const size_t gbase = (size_t)(tok0 + m) * DIM + n0;
      const float4 x4 = *(const float4*)&x[gbase];
      float4 o;
      o.x = fmaf((float)acc2[t][mt][0], r2, b4.x + x4.x);
      o.y = fmaf((float)acc2[t][mt][1], r2, b4.y + x4.y);
      o.z = fmaf((float)acc2[t][mt][2], r2, b4.z + x4.z);
      o.w = fmaf((float)acc2[t][mt][3], r2, b4.w + x4.w);
      *(float4*)&out[gbase] = o;
    }
  }
}

extern "C" void kernel_launch(void* const* d_in, const int* in_sizes, int n_in,
                              void* d_out, int out_size, void* d_ws, size_t ws_size,
                              hipStream_t stream) {
  const float* x  = (const float*)d_in[0];
  const float* w1 = (const float*)d_in[1];
  const float* b1 = (const float*)d_in[2];
  const float* w2 = (const float*)d_in[3];
  const float* b2 = (const float*)d_in[4];
  float* out = (float*)d_out;

  float* wpart   = (float*)d_ws;
  float* wscales = wpart + 512;
  signed char* p1 = (signed char*)((char*)d_ws + 4096);
  signed char* p2 = (signed char*)((char*)d_ws + 4096 + 1048576);

  k_wabs<<<512, 256, 0, stream>>>(w1, w2, wpart);
  k_pack<<<512, 256, 0, stream>>>(w1, w2, wpart, wscales, p1, p2);
  k_fused<<<1024, 1024, 0, stream>>>(x, b1, b2, p1, p2, wscales, out);
}

// Round 17
// 289.936 us; speedup vs baseline: 1.2310x; 1.2310x over previous
//
#include <hip/hip_runtime.h>
#include <hip/hip_bf16.h>

#define DIM 512
#define HID 2048
#define MT  64
#define KS1 8     // 512/64  k-steps GEMM1 (i8 K=64)
#define KS2 32    // 2048/64 k-steps GEMM2

typedef __attribute__((ext_vector_type(4))) int      i32x4;
typedef __attribute__((ext_vector_type(4))) unsigned u32x4;

// branch-free exact-erf GELU via Abramowitz-Stegun 7.1.26 (abs err 1.5e-7)
static __device__ __forceinline__ float gelu_erf(float h) {
  const float u  = h * 0.70710678118654752f;
  const float au = fabsf(u);
  const float t  = __builtin_amdgcn_rcpf(fmaf(0.3275911f, au, 1.f));
  float p = fmaf(1.061405429f, t, -1.453152027f);
  p = fmaf(p, t, 1.421413741f);
  p = fmaf(p, t, -0.284496736f);
  p = fmaf(p, t, 0.254829592f);
  p *= t;
  const float e  = __builtin_amdgcn_exp2f(-u * u * 1.4426950408889634f);  // exp(-u^2)
  const float ea = fmaf(-p, e, 1.f);                                      // erf(|u|)
  const float er = __builtin_copysignf(ea, u);
  return fmaf(0.5f * h, er, 0.5f * h);
}

static __device__ __forceinline__ int qi8(float g, float s) {
  return (int)fminf(fmaxf(rintf(g * s), -128.f), 127.f);
}

static __device__ __forceinline__ unsigned q4pack(float4 v, float scl) {
  int q0 = qi8(v.x, scl), q1 = qi8(v.y, scl), q2 = qi8(v.z, scl), q3 = qi8(v.w, scl);
  return (unsigned)(q0 & 255) | ((unsigned)(q1 & 255) << 8) |
         ((unsigned)(q2 & 255) << 16) | ((unsigned)(q3 & 255) << 24);
}

// ---------------- K0: per-block partial sums of |w| ----------------
__global__ void k_wabs(const float* __restrict__ w1, const float* __restrict__ w2,
                       float* __restrict__ part) {
  const int b = blockIdx.x;
  const float* src = (b < 256 ? w1 : w2) + (size_t)(b & 255) * 4096 + threadIdx.x * 16;
  float s = 0.f;
#pragma unroll
  for (int i = 0; i < 4; ++i) {
    float4 v = *(const float4*)(src + i * 4);
    s += fabsf(v.x) + fabsf(v.y) + fabsf(v.z) + fabsf(v.w);
  }
  __shared__ float red[256];
  red[threadIdx.x] = s;
  __syncthreads();
  for (int off = 128; off > 0; off >>= 1) {
    if (threadIdx.x < (unsigned)off) red[threadIdx.x] += red[threadIdx.x + off];
    __syncthreads();
  }
  if (threadIdx.x == 0) part[b] = red[0];
}

// ---------------- K1: reduce partials (redundant per block, deterministic),
// ternary-quantize weights, pack i8 MFMA fragments.
// frag (nt,ks): lane l holds w[nt*16+(l&15)][ks*64+(l>>4)*16 + j], j=0..15
__global__ void k_pack(const float* __restrict__ w1, const float* __restrict__ w2,
                       const float* __restrict__ part, float* __restrict__ scales,
                       signed char* __restrict__ p1, signed char* __restrict__ p2) {
  __shared__ float s1[256], s2[256];
  s1[threadIdx.x] = part[threadIdx.x];
  s2[threadIdx.x] = part[256 + threadIdx.x];
  __syncthreads();
  for (int off = 128; off > 0; off >>= 1) {
    if (threadIdx.x < (unsigned)off) {
      s1[threadIdx.x] += s1[threadIdx.x + off];
      s2[threadIdx.x] += s2[threadIdx.x + off];
    }
    __syncthreads();
  }
  const float mc1 = fmaxf(s1[0] / 1048576.f, 1e-5f);
  const float mc2 = fmaxf(s2[0] / 1048576.f, 1e-5f);
  if (blockIdx.x == 0 && threadIdx.x == 0) {
    scales[0] = mc1;
    scales[2] = mc2;
  }

  int slot = blockIdx.x * 256 + threadIdx.x;    // 0..131071 (first 65536 -> p1)
  const bool isw2 = slot >= 65536;
  const float* w = isw2 ? w2 : w1;
  const float scl = 1.f / (isw2 ? mc2 : mc1);
  signed char* p = isw2 ? p2 : p1;
  const int K  = isw2 ? HID : DIM;
  const int KS = isw2 ? KS2 : KS1;
  slot &= 65535;
  const int lane = slot & 63;
  const int fr   = slot >> 6;
  const int nt   = fr / KS;
  const int ks   = fr - nt * KS;
  const int n  = nt * 16 + (lane & 15);
  const int k0 = ks * 64 + (lane >> 4) * 16;
  const float* src = w + (size_t)n * K + k0;
  i32x4 outv;
#pragma unroll
  for (int d = 0; d < 4; ++d) {
    unsigned v = 0;
#pragma unroll
    for (int e = 0; e < 4; ++e) {
      int q = (int)fminf(fmaxf(rintf(src[d * 4 + e] * scl), -1.f), 1.f);
      v |= ((unsigned)(q & 255)) << (8 * e);
    }
    outv[d] = (int)v;
  }
  *(i32x4*)(p + (size_t)slot * 16) = outv;
}

// ---------------- K2: fused quant -> GEMM1(i8, two-pass, swapped-MFMA) ->
// GELU -> quant -> GEMM2(i8, swapped) -> residual.   [R9 structure, verified]
// MT=64, 16 waves (1024 thr), 4 waves/SIMD, LDS = 128KB qh + 32KB xq.
// Swapped mfma(B,A) => lane owns ONE token row per mt and 4 consecutive
// output cols per tile: scalar row scales, b32 LDS writes, float4 C stores.
__global__ __launch_bounds__(1024, 4) void k_fused(
    const float* __restrict__ x, const float* __restrict__ b1,
    const float* __restrict__ b2, const signed char* __restrict__ p1,
    const signed char* __restrict__ p2, const float* __restrict__ scales,
    float* __restrict__ out) {
  __shared__ __align__(16) signed char qh[131072];   // 64x2048 i8 (written in pass2)
  __shared__ __align__(16) signed char xq[32768];    // 64x512  i8 (swizzled)

  // scratch aliased into qh (dead until pass2 writes it; consumed before):
  float* rxTab = (float*)qh;                 // [64]    recip_x*wsc1
  float* scrP  = (float*)(qh + 1024);        // [16*64] hvmax partials
  float* scrQ  = (float*)(qh + 5120);        // [16*64] hvmin partials
  float* scrS  = (float*)(qh + 9216);        // [64]    127/maxg

  const int tid = threadIdx.x;
  const int wv = tid >> 6, ln = tid & 63, lg = ln >> 4, lr = ln & 15;
  const int tok0 = blockIdx.x * MT;
  const float wsc1 = scales[0], wsc2 = scales[2];
  const int swz = (lr & 7) << 4;             // row swizzle (row = mt*16+lr)

  // ---- phase 1: load x, per-token absmax int8 quant -> xq (swizzled)
  {
    const int row = tid >> 4, sub = tid & 15;      // 16 threads per 512-float row
    const float4* xr = (const float4*)(x + (size_t)(tok0 + row) * DIM);
    float4 v[8];
    float am = 0.f;
#pragma unroll
    for (int i = 0; i < 8; ++i) {
      v[i] = xr[i * 16 + sub];
      am = fmaxf(am, fmaxf(fmaxf(fabsf(v[i].x), fabsf(v[i].y)),
                           fmaxf(fabsf(v[i].z), fabsf(v[i].w))));
    }
#pragma unroll
    for (int m = 1; m < 16; m <<= 1) am = fmaxf(am, __shfl_xor(am, m));
    const float mc  = fmaxf(am, 1e-5f);
    const float scl = 127.f / mc;
    if (sub == 0) rxTab[row] = mc * (1.f / 127.f) * wsc1;
    const int rswz = (row & 7) << 4;
#pragma unroll
    for (int i = 0; i < 8; ++i) {
      const unsigned u = q4pack(v[i], scl);
      const int k = i * 64 + sub * 4;
      *(unsigned*)&xq[row * DIM + (((k & ~15) ^ rswz) | (k & 15))] = u;
    }
  }
  __syncthreads();

  float rxw[4];
#pragma unroll
  for (int mt = 0; mt < 4; ++mt) rxw[mt] = rxTab[mt * 16 + lr];

  // ---- GEMM1 pass 1 (swapped): track per-row h min/max only
  float hvmax[4], hvmin[4];
#pragma unroll
  for (int mt = 0; mt < 4; ++mt) { hvmax[mt] = -3.4e38f; hvmin[mt] = 3.4e38f; }

#pragma unroll 1
  for (int ch = 0; ch < 4; ++ch) {
    i32x4 acc[2][4];
#pragma unroll
    for (int t = 0; t < 2; ++t)
#pragma unroll
      for (int mt = 0; mt < 4; ++mt) acc[t][mt] = (i32x4){0, 0, 0, 0};
#pragma unroll 2
    for (int ks = 0; ks < KS1; ++ks) {
      i32x4 a[4];
#pragma unroll
      for (int mt = 0; mt < 4; ++mt)
        a[mt] = *(const i32x4*)&xq[(mt * 16 + lr) * DIM + ((ks * 64 + lg * 16) ^ swz)];
#pragma unroll
      for (int t = 0; t < 2; ++t) {
        const int ntg = wv * 8 + ch * 2 + t;
        const i32x4 bfr = *(const i32x4*)(p1 + ((size_t)(ntg * KS1 + ks) * 64 + ln) * 16);
#pragma unroll
        for (int mt = 0; mt < 4; ++mt)
          acc[t][mt] = __builtin_amdgcn_mfma_i32_16x16x64_i8(bfr, a[mt], acc[t][mt], 0, 0, 0);
      }
    }
#pragma unroll
    for (int t = 0; t < 2; ++t) {
      const int ntg = wv * 8 + ch * 2 + t;
      const float4 b4 = *(const float4*)&b1[ntg * 16 + lg * 4];
#pragma unroll
      for (int mt = 0; mt < 4; ++mt) {
#pragma unroll
        for (int r = 0; r < 4; ++r) {
          const float bias = r == 0 ? b4.x : r == 1 ? b4.y : r == 2 ? b4.z : b4.w;
          const float hv = fmaf((float)acc[t][mt][r], rxw[mt], bias);
          hvmax[mt] = fmaxf(hvmax[mt], hv);
          hvmin[mt] = fminf(hvmin[mt], hv);
        }
      }
    }
  }

  // ---- reduce per-row h range (rows = mt*16+lr; partners at lane^16, ^32)
#pragma unroll
  for (int mt = 0; mt < 4; ++mt) {
    hvmax[mt] = fmaxf(hvmax[mt], __shfl_xor(hvmax[mt], 16));
    hvmax[mt] = fmaxf(hvmax[mt], __shfl_xor(hvmax[mt], 32));
    hvmin[mt] = fminf(hvmin[mt], __shfl_xor(hvmin[mt], 16));
    hvmin[mt] = fminf(hvmin[mt], __shfl_xor(hvmin[mt], 32));
  }
  if (ln < 16) {
#pragma unroll
    for (int mt = 0; mt < 4; ++mt) {
      scrP[wv * 64 + mt * 16 + lr] = hvmax[mt];
      scrQ[wv * 64 + mt * 16 + lr] = hvmin[mt];
    }
  }
  __syncthreads();
  if (tid < MT) {
    float hx = scrP[tid], hn = scrQ[tid];
#pragma unroll
    for (int w = 1; w < 16; ++w) {
      hx = fmaxf(hx, scrP[w * 64 + tid]);
      hn = fminf(hn, scrQ[w * 64 + tid]);
    }
    // max|gelu| over the row: gelu monotone increasing on [-0.7518, inf),
    // |gelu| <= 0.1699705 for h <= -0.7518.
    const float posg = gelu_erf(hx);
    const float negg = (hn <= -0.7518f) ? 0.1699705f : fabsf(gelu_erf(hn));
    const float mg = fmaxf(fmaxf(posg, negg), 1e-5f);
    scrS[tid] = 127.f / mg;
  }
  __syncthreads();

  float s2w[4];
#pragma unroll
  for (int mt = 0; mt < 4; ++mt) s2w[mt] = scrS[mt * 16 + lr];
  __syncthreads();   // all scratch reads done before pass2 overwrites qh

  // ---- GEMM1 pass 2: recompute (bit-identical), GELU, quantize -> qh i8
#pragma unroll 1
  for (int ch = 0; ch < 4; ++ch) {
    i32x4 acc[2][4];
#pragma unroll
    for (int t = 0; t < 2; ++t)
#pragma unroll
      for (int mt = 0; mt < 4; ++mt) acc[t][mt] = (i32x4){0, 0, 0, 0};
#pragma unroll 2
    for (int ks = 0; ks < KS1; ++ks) {
      i32x4 a[4];
#pragma unroll
      for (int mt = 0; mt < 4; ++mt)
        a[mt] = *(const i32x4*)&xq[(mt * 16 + lr) * DIM + ((ks * 64 + lg * 16) ^ swz)];
#pragma unroll
      for (int t = 0; t < 2; ++t) {
        const int ntg = wv * 8 + ch * 2 + t;
        const i32x4 bfr = *(const i32x4*)(p1 + ((size_t)(ntg * KS1 + ks) * 64 + ln) * 16);
#pragma unroll
        for (int mt = 0; mt < 4; ++mt)
          acc[t][mt] = __builtin_amdgcn_mfma_i32_16x16x64_i8(bfr, a[mt], acc[t][mt], 0, 0, 0);
      }
    }
#pragma unroll
    for (int t = 0; t < 2; ++t) {
      const int ntg = wv * 8 + ch * 2 + t;
      const float4 b4 = *(const float4*)&b1[ntg * 16 + lg * 4];
#pragma unroll
      for (int mt = 0; mt < 4; ++mt) {
        const int m = mt * 16 + lr;
        unsigned pk = 0;
#pragma unroll
        for (int r = 0; r < 4; ++r) {
          const float bias = r == 0 ? b4.x : r == 1 ? b4.y : r == 2 ? b4.z : b4.w;
          const float hv = fmaf((float)acc[t][mt][r], rxw[mt], bias);
          const float g  = gelu_erf(hv);
          pk |= ((unsigned)(qi8(g, s2w[mt]) & 255)) << (8 * r);
        }
        // 4 consecutive cols n0..n0+3, n0 = ntg*16 + lg*4 (swizzle-consistent)
        *(unsigned*)&qh[m * HID + (((ntg * 16) ^ ((m & 7) << 4)) + lg * 4)] = pk;
      }
    }
  }
  __syncthreads();

  // ---- GEMM2 (swapped): [64 x 512] i8; wave owns 2 n-tiles
  i32x4 acc2[2][4];
#pragma unroll
  for (int t = 0; t < 2; ++t)
#pragma unroll
    for (int mt = 0; mt < 4; ++mt) acc2[t][mt] = (i32x4){0, 0, 0, 0};
#pragma unroll 2
  for (int ks = 0; ks < KS2; ++ks) {
    i32x4 a[4];
#pragma unroll
    for (int mt = 0; mt < 4; ++mt)
      a[mt] = *(const i32x4*)&qh[(mt * 16 + lr) * HID + ((ks * 64 + lg * 16) ^ swz)];
#pragma unroll
    for (int t = 0; t < 2; ++t) {
      const int nt = wv * 2 + t;
      const i32x4 bfr = *(const i32x4*)(p2 + ((size_t)(nt * KS2 + ks) * 64 + ln) * 16);
#pragma unroll
      for (int mt = 0; mt < 4; ++mt)
        acc2[t][mt] = __builtin_amdgcn_mfma_i32_16x16x64_i8(bfr, a[mt], acc2[t][mt], 0, 0, 0);
    }
  }
#pragma unroll
  for (int t = 0; t < 2; ++t) {
    const int n0 = (wv * 2 + t) * 16 + lg * 4;
    const float4 b4 = *(const float4*)&b2[n0];
#pragma unroll
    for (int mt = 0; mt < 4; ++mt) {
      const int m = mt * 16 + lr;
      const float r2 = wsc2 * __builtin_amdgcn_rcpf(s2w[mt]);  // = maxg/127*wsc2
      const size_t gbase = (size_t)(tok0 + m) * DIM + n0;
      const float4 x4 = *(const float4*)&x[gbase];
      float4 o;
      o.x = fmaf((float)acc2[t][mt][0], r2, b4.x + x4.x);
      o.y = fmaf((float)acc2[t][mt][1], r2, b4.y + x4.y);
      o.z = fmaf((float)acc2[t][mt][2], r2, b4.z + x4.z);
      o.w = fmaf((float)acc2[t][mt][3], r2, b4.w + x4.w);
      *(float4*)&out[gbase] = o;
    }
  }
}

extern "C" void kernel_launch(void* const* d_in, const int* in_sizes, int n_in,
                              void* d_out, int out_size, void* d_ws, size_t ws_size,
                              hipStream_t stream) {
  const float* x  = (const float*)d_in[0];
  const float* w1 = (const float*)d_in[1];
  const float* b1 = (const float*)d_in[2];
  const float* w2 = (const float*)d_in[3];
  const float* b2 = (const float*)d_in[4];
  float* out = (float*)d_out;

  float* wpart   = (float*)d_ws;
  float* wscales = wpart + 512;
  signed char* p1 = (signed char*)((char*)d_ws + 4096);
  signed char* p2 = (signed char*)((char*)d_ws + 4096 + 1048576);

  k_wabs<<<512, 256, 0, stream>>>(w1, w2, wpart);
  k_pack<<<512, 256, 0, stream>>>(w1, w2, wpart, wscales, p1, p2);
  k_fused<<<1024, 1024, 0, stream>>>(x, b1, b2, p1, p2, wscales, out);
}